// Round 9
// baseline (229.204 us; speedup 1.0000x reference)
//
#include <hip/hip_runtime.h>
#include <cstdint>
#include <cstddef>

#define SEQ   2048
#define EDIM  256
#define FFND  512
#define NBATCH 16
#define XLD   264   // xt row pitch (u16)

typedef unsigned short u16;
typedef __attribute__((ext_vector_type(8))) __bf16 bf16x8;
typedef __attribute__((ext_vector_type(4))) float f32x4;

__device__ __forceinline__ float bf2f(u16 u) {
  union { unsigned int w; float f; } v; v.w = ((unsigned int)u) << 16; return v.f;
}
__device__ __forceinline__ u16 f2bf(float f) {
  union { float f; unsigned int w; } v; v.f = f;
  unsigned int r = v.w + 0x7fffu + ((v.w >> 16) & 1u);
  return (u16)(r >> 16);
}
__device__ __forceinline__ float fast_cos(float x) {
  float r = x * 0.15915494309189535f;
  r = r - floorf(r);
  return __builtin_amdgcn_cosf(r);
}
__device__ __forceinline__ void unpack8(bf16x8 v, float* o) {
  const u16* p = (const u16*)&v;
  #pragma unroll
  for (int j = 0; j < 8; ++j) o[j] = bf2f(p[j]);
}

// -------- sniff: float inputs f32 (flag=1) or bf16 (flag=0) --------
__global__ void sniff_kernel(const void* embed, int* flag) {
  int t = threadIdx.x;
  const u16* p = (const u16*)embed;
  int c = 0;
  #pragma unroll
  for (int j = 0; j < 8; ++j) {
    u16 v = p[t * 8 + j];
    int e = (v >> 7) & 0xff;
    c += (e > 128) ? 1 : 0;
  }
  #pragma unroll
  for (int d = 1; d < 64; d <<= 1) c += __shfl_xor(c, d);
  if (t == 0) *flag = (c > 64) ? 1 : 0;
}

// -------- canonicalize all small float params to bf16 in ws --------
struct CanonArgs { const void* p[14]; };

__global__ void canon_kernel(CanonArgs a, const int* __restrict__ flag, u16* __restrict__ dst) {
  const int off[15] = {0, 128, 131200, 131712, 131728, 139920, 140944, 403088,
                       403600, 404112, 404624, 405136, 405648, 406160, 406162};
  int i = blockIdx.x * 256 + threadIdx.x;
  if (i >= 406162) return;
  int isf32 = *flag;
  int s = 0;
  #pragma unroll
  for (int k = 0; k < 13; ++k) s += (i >= off[k + 1]) ? 1 : 0;
  int j = i - off[s];
  u16 v = isf32 ? f2bf(((const float*)a.p[s])[j]) : ((const u16*)a.p[s])[j];
  dst[i] = v;
}

// ---- prep: cwT/l2T to staging layout [K/8][256][8]; w1T[c][n] = W1[n][c] ----
__global__ void prep_kernel(const u16* __restrict__ cw, const u16* __restrict__ l2,
                            const u16* __restrict__ w1, u16* __restrict__ cwT,
                            u16* __restrict__ l2T, u16* __restrict__ w1T) {
  int id = blockIdx.x * 256 + threadIdx.x;
  if (id < 131072) {
    int l = id >> 16, rem = id & 65535;
    int kc = rem >> 11, n = (rem >> 3) & 255, kj = rem & 7;
    cwT[id] = cw[l * 65536 + (kc * 8 + kj) * 256 + n];
  } else if (id < 393216) {
    int j = id - 131072;
    int l = j >> 17, rem = j & 131071;
    int kc = rem >> 11, n = (rem >> 3) & 255, kj = rem & 7;
    l2T[j] = l2[l * 131072 + (kc * 8 + kj) * 256 + n];
  } else if (id < 401408) {
    int j = id - 393216;
    int l = j >> 12, rem = j & 4095;
    int c = rem >> 3, n = rem & 7;
    w1T[j] = w1[l * 4096 + n * 512 + c];
  }
}

// ---- PE table: pe[s][e] f32, s<2048, e<256 ----
__global__ void pe_kernel(float* __restrict__ pe) {
  int id = blockIdx.x * 256 + threadIdx.x;   // 524288 elems
  int s = id >> 8, e = id & 255;
  const float c0 = 9.210340371976184f / 128.f;
  const float inv2pi = 0.15915494309189535f;
  int i = e >> 1;
  float rev = (float)s * (__expf(-(float)i * c0) * inv2pi);
  rev = rev - floorf(rev);
  pe[id] = (e & 1) ? __builtin_amdgcn_cosf(rev) : __builtin_amdgcn_sinf(rev);
}

// ====== MEGA: embed+PE -> [attn GEMM+LN1 -> q -> ffn(h via MFMA) GEMM+LN2] x2 -> pool ======
__launch_bounds__(256, 2)
__global__ void mega_kernel(const int* __restrict__ tokens, const void* __restrict__ embed,
                            const int* __restrict__ flag, const u16* __restrict__ canon,
                            const u16* __restrict__ cwT, const u16* __restrict__ l2T,
                            const u16* __restrict__ w1T, const float* __restrict__ pe,
                            float* __restrict__ pooled) {
  __shared__ u16 xt[64 * XLD];          // 33792 B persistent x tile
  __shared__ union {
    struct { u16 Bt[256 * 64]; u16 At[64 * 64]; u16 qs[64 * 8]; } k;  // 41984 B
    struct { float2 part[64][65]; float2 ms[64]; } ln;                 // 33792 B
  } sh;
  __shared__ u16 thL[64];

  const int tid = threadIdx.x;
  const int wave = tid >> 6, lane = tid & 63;
  const int fr = lane & 15, fq = lane >> 4;
  const int m0 = blockIdx.x * 64;
  const int isf32 = *flag;

  int cols[4];
  #pragma unroll
  for (int ni = 0; ni < 4; ++ni) cols[ni] = wave * 64 + ni * 16 + fr;

  // ---------- embed + PE-table -> xt ----------
  #pragma unroll
  for (int it = 0; it < 8; ++it) {
    int c = it * 256 + tid;
    int r = c >> 5, e8 = c & 31;
    int tok = tokens[m0 + r];
    float ev[8];
    if (isf32) {
      const float* ep = (const float*)embed + (size_t)tok * EDIM + e8 * 8;
      float4 a = *(const float4*)ep, b = *(const float4*)(ep + 4);
      ev[0]=a.x; ev[1]=a.y; ev[2]=a.z; ev[3]=a.w; ev[4]=b.x; ev[5]=b.y; ev[6]=b.z; ev[7]=b.w;
    } else {
      const u16* ep = (const u16*)embed + (size_t)tok * EDIM + e8 * 8;
      uint4 v = *(const uint4*)ep;
      unpack8(*(const bf16x8*)&v, ev);
    }
    int s = (m0 + r) & (SEQ - 1);
    const float* pp = pe + s * EDIM + e8 * 8;
    float4 p0 = *(const float4*)pp, p1 = *(const float4*)(pp + 4);
    float pv[8] = {p0.x, p0.y, p0.z, p0.w, p1.x, p1.y, p1.z, p1.w};
    u16 o[8];
    #pragma unroll
    for (int j = 0; j < 8; ++j) o[j] = f2bf(ev[j] + pv[j]);
    *(uint4*)(xt + r * XLD + e8 * 8) = *(const uint4*)o;
  }
  __syncthreads();

  f32x4 acc[4][4];

  auto mfma_step = [&]() {
    const bf16x8* Av = (const bf16x8*)sh.k.At;
    const bf16x8* Bv = (const bf16x8*)sh.k.Bt;
    #pragma unroll
    for (int ks = 0; ks < 2; ++ks) {
      const int kc = ks * 4 + fq;
      bf16x8 af[4], bfv[4];
      #pragma unroll
      for (int mi = 0; mi < 4; ++mi) af[mi] = Av[kc * 64 + ((mi * 16 + fr) ^ kc)];
      #pragma unroll
      for (int ni = 0; ni < 4; ++ni) bfv[ni] = Bv[kc * 256 + cols[ni]];
      #pragma unroll
      for (int mi = 0; mi < 4; ++mi)
        #pragma unroll
        for (int ni = 0; ni < 4; ++ni)
          acc[mi][ni] = __builtin_amdgcn_mfma_f32_16x16x32_bf16(af[mi], bfv[ni], acc[mi][ni], 0, 0, 0);
    }
  };

  // bias + residual + LN (partial-dump reduction; no shuffles)
  auto epilogue = [&](const u16* bias, const u16* gamma, const u16* beta) {
    float bcol[4];
    #pragma unroll
    for (int ni = 0; ni < 4; ++ni) bcol[ni] = bf2f(bias[cols[ni]]);
    #pragma unroll
    for (int mi = 0; mi < 4; ++mi)
      #pragma unroll
      for (int rg = 0; rg < 4; ++rg) {
        int lrow = mi * 16 + fq * 4 + rg;
        float a = 0.f, b = 0.f;
        #pragma unroll
        for (int ni = 0; ni < 4; ++ni) {
          float t2 = acc[mi][ni][rg] + bf2f(xt[lrow * XLD + cols[ni]]) + bcol[ni];
          acc[mi][ni][rg] = t2;
          a += t2; b += t2 * t2;
        }
        sh.ln.part[lrow][wave * 16 + fr] = float2{a, b};
      }
    __syncthreads();
    if (tid < 64) {
      float s = 0.f, s2 = 0.f;
      #pragma unroll
      for (int f = 0; f < 64; f += 2) {
        float4 p = *(const float4*)&sh.ln.part[tid][f];
        s += p.x + p.z; s2 += p.y + p.w;
      }
      float mean = s * (1.f / 256.f);
      float var = fmaxf(s2 * (1.f / 256.f) - mean * mean, 0.f);
      sh.ln.ms[tid] = float2{mean, rsqrtf(var + 1e-5f)};
    }
    __syncthreads();
    float gcol[4], btc[4];
    #pragma unroll
    for (int ni = 0; ni < 4; ++ni) { gcol[ni] = bf2f(gamma[cols[ni]]); btc[ni] = bf2f(beta[cols[ni]]); }
    #pragma unroll
    for (int mi = 0; mi < 4; ++mi)
      #pragma unroll
      for (int rg = 0; rg < 4; ++rg) {
        int lrow = mi * 16 + fq * 4 + rg;
        float2 ms = sh.ln.ms[lrow];
        #pragma unroll
        for (int ni = 0; ni < 4; ++ni) {
          float o = (acc[mi][ni][rg] - ms.x) * ms.y * gcol[ni] + btc[ni];
          xt[lrow * XLD + cols[ni]] = f2bf(o);
        }
      }
    __syncthreads();
  };

  for (int l = 0; l < 2; ++l) {
    // ---------- attn: acc = cos(xt + theta) @ cwT ----------
    if (tid < 8) ((uint4*)thL)[tid] = ((const uint4*)(canon + l * 64))[tid];
    __syncthreads();
    #pragma unroll
    for (int i = 0; i < 4; ++i)
      #pragma unroll
      for (int j = 0; j < 4; ++j) acc[i][j] = {0.f, 0.f, 0.f, 0.f};
    {
      const u16* Bbase = cwT + l * 65536;
      for (int k0 = 0; k0 < 256; k0 += 64) {
        const u16* bsrc = Bbase + (k0 >> 3) * 2048;
        #pragma unroll
        for (int it = 0; it < 8; ++it) {
          int c = tid + it * 256;
          __builtin_amdgcn_global_load_lds(
              (const __attribute__((address_space(1))) void*)(bsrc + (size_t)c * 8),
              (__attribute__((address_space(3))) void*)(sh.k.Bt + c * 8), 16, 0, 0);
        }
        #pragma unroll
        for (int it = 0; it < 2; ++it) {
          int c = it * 256 + tid;
          int f8 = c >> 6, r = c & 63;
          uint4 g = *(const uint4*)(xt + r * XLD + k0 + f8 * 8);
          u16* gp = (u16*)&g;
          #pragma unroll
          for (int j = 0; j < 8; ++j)
            gp[j] = f2bf(fast_cos(bf2f(gp[j]) + bf2f(thL[f8 * 8 + j])));
          ((uint4*)sh.k.At)[f8 * 64 + (r ^ f8)] = g;
        }
        __syncthreads();
        mfma_step();
        __syncthreads();
      }
    }
    epilogue(canon + 131200 + l * 256, canon + 403600 + l * 256, canon + 404112 + l * 256);

    // ---------- q = cos(xt[:, :8]) * cos(ffn_theta) -> qs (bf16) ----------
    #pragma unroll
    for (int rep = 0; rep < 2; ++rep) {
      int idx = tid + rep * 256;
      int r = idx >> 3, n = idx & 7;
      float cth = fast_cos(bf2f(canon[131712 + l * 8 + n]));
      sh.k.qs[r * 8 + n] = f2bf(fast_cos(bf2f(xt[r * XLD + n])) * cth);
    }
    __syncthreads();

    // A-frags of q (K padded 8->32: fq>0 lanes zero); held in regs across k-loop
    bf16x8 af_q[4];
    #pragma unroll
    for (int mi = 0; mi < 4; ++mi) {
      uint4 qv = {0u, 0u, 0u, 0u};
      if (fq == 0) qv = *(const uint4*)(sh.k.qs + (mi * 16 + fr) * 8);
      af_q[mi] = *(const bf16x8*)&qv;
    }

    // ---------- ffn: h = relu(q @ W1 + b1) via MFMA; acc += h @ l2T ----------
    #pragma unroll
    for (int i = 0; i < 4; ++i)
      #pragma unroll
      for (int j = 0; j < 4; ++j) acc[i][j] = {0.f, 0.f, 0.f, 0.f};
    {
      const u16* B2 = l2T + l * 131072;
      const u16* w1t = w1T + l * 4096;
      const u16* b1 = canon + 139920 + l * 512;
      for (int k0 = 0; k0 < 512; k0 += 64) {
        const u16* bsrc = B2 + (k0 >> 3) * 2048;
        #pragma unroll
        for (int it = 0; it < 8; ++it) {
          int c = tid + it * 256;
          __builtin_amdgcn_global_load_lds(
              (const __attribute__((address_space(1))) void*)(bsrc + (size_t)c * 8),
              (__attribute__((address_space(3))) void*)(sh.k.Bt + c * 8), 16, 0, 0);
        }
        // h-tile via MFMA: D(r=fq*4+rg+16mi, c=k0+ni*16+fr)
        f32x4 acc2[4][4];
        #pragma unroll
        for (int ni = 0; ni < 4; ++ni) {
          float b1v = bf2f(b1[k0 + ni * 16 + fr]);
          #pragma unroll
          for (int mi = 0; mi < 4; ++mi) acc2[mi][ni] = {b1v, b1v, b1v, b1v};
        }
        #pragma unroll
        for (int ni = 0; ni < 4; ++ni) {
          uint4 wv = {0u, 0u, 0u, 0u};
          if (fq == 0) wv = *(const uint4*)(w1t + (size_t)(k0 + ni * 16 + fr) * 8);
          bf16x8 bfw = *(const bf16x8*)&wv;
          #pragma unroll
          for (int mi = 0; mi < 4; ++mi)
            acc2[mi][ni] = __builtin_amdgcn_mfma_f32_16x16x32_bf16(af_q[mi], bfw, acc2[mi][ni], 0, 0, 0);
        }
        // relu + repack into At (XOR chunk layout)
        #pragma unroll
        for (int mi = 0; mi < 4; ++mi)
          #pragma unroll
          for (int ni = 0; ni < 4; ++ni) {
            int kk = ni * 16 + fr, kc = kk >> 3;
            #pragma unroll
            for (int rg = 0; rg < 4; ++rg) {
              int r = mi * 16 + fq * 4 + rg;
              sh.k.At[(kc * 64 + (r ^ kc)) * 8 + (kk & 7)] = f2bf(fmaxf(acc2[mi][ni][rg], 0.f));
            }
          }
        __syncthreads();
        mfma_step();
        __syncthreads();
      }
    }
    epilogue(canon + 403088 + l * 256, canon + 404624 + l * 256, canon + 405136 + l * 256);
  }

  // ---------- pool ----------
  {
    float s = 0.f;
    #pragma unroll 8
    for (int r = 0; r < 64; ++r) s += bf2f(xt[r * XLD + tid]);
    atomicAdd(&pooled[(m0 >> 11) * EDIM + tid], s);
  }
}

__global__ void logits_kernel(const float* __restrict__ pooled, const u16* __restrict__ clsw,
                              const u16* __restrict__ clsb, const int* __restrict__ flag,
                              void* __restrict__ out) {
  int t = threadIdx.x;
  int b = t >> 4, sub = t & 15;
  float a0 = 0.f, a1 = 0.f;
  #pragma unroll
  for (int j = 0; j < 16; ++j) {
    int e = sub * 16 + j;
    float p = pooled[b * 256 + e];
    a0 += p * bf2f(clsw[e * 2 + 0]);
    a1 += p * bf2f(clsw[e * 2 + 1]);
  }
  #pragma unroll
  for (int d = 1; d < 16; d <<= 1) {
    a0 += __shfl_xor(a0, d);
    a1 += __shfl_xor(a1, d);
  }
  if (sub == 0) {
    float o0 = a0 * (1.f / 2048.f) + bf2f(clsb[0]);
    float o1 = a1 * (1.f / 2048.f) + bf2f(clsb[1]);
    if (*flag) {
      ((float*)out)[b * 2 + 0] = o0; ((float*)out)[b * 2 + 1] = o1;
    } else {
      ((u16*)out)[b * 2 + 0] = f2bf(o0); ((u16*)out)[b * 2 + 1] = f2bf(o1);
    }
  }
}

extern "C" void kernel_launch(void* const* d_in, const int* in_sizes, int n_in,
                              void* d_out, int out_size, void* d_ws, size_t ws_size,
                              hipStream_t stream) {
  const int* tokens = (const int*)d_in[0];

  char* ws = (char*)d_ws;
  u16*   canon  = (u16*)(ws + 0);              // 812 KB bf16 params
  u16*   cwT    = (u16*)(ws + 1048576);        // 256 KB
  u16*   l2T    = (u16*)(ws + 1310720);        // 512 KB
  u16*   w1T    = (u16*)(ws + 1835008);        //  16 KB  [2][512][8]
  float* pooled = (float*)(ws + 1851392);      //  16 KB
  int*   flag   = (int*)(ws + 1867776);        //   4 B
  float* pe     = (float*)(ws + 2097152);      //   2 MB  [2048][256] f32

  sniff_kernel<<<1, 64, 0, stream>>>(d_in[1], flag);

  CanonArgs ca;
  for (int i = 0; i < 14; ++i) ca.p[i] = d_in[i + 2];
  canon_kernel<<<1587, 256, 0, stream>>>(ca, flag, canon);

  pe_kernel<<<2048, 256, 0, stream>>>(pe);
  prep_kernel<<<1568, 256, 0, stream>>>(canon + 128, canon + 140944, canon + 131728,
                                        cwT, l2T, w1T);

  hipMemsetAsync(pooled, 0, NBATCH * EDIM * sizeof(float), stream);

  mega_kernel<<<512, 256, 0, stream>>>(tokens, d_in[1], flag, canon, cwT, l2T, w1T, pe, pooled);

  logits_kernel<<<1, 256, 0, stream>>>(pooled, canon + 405648, canon + 406160, flag, d_out);
}